// Round 16
// baseline (79.005 us; speedup 1.0000x reference)
//
#include <hip/hip_runtime.h>

// dist[pix, o] = ||x[pix]||^2 + ||omega[o]||^2 - 2 * x.omega
// M = 262144 pixels, O = 256 protos, D = 64.
// Round-16: EXACT round-13 structure (32x32x16 MFMA, A=x / B=omega, nt
// full-granule-ish loads, scalar dword stores with 32-lane contiguous runs =
// full 128B line requests, omega frags in LDS, interleaved per-T stores,
// 4 blocks/CU). Single change: stores NONTEMPORAL. R5's nt-store penalty was
// specific to 64B partial-line requests (nt bypassed the L2 merge). Here
// every store request is a full 128B line -> no merge needed; nt =
// write-through/no-allocate -> 268MB of dirty lines stop churning the 32MB
// L2, writeback pressure disappears, and the x read stream stops being
// evicted (granule-half re-reads hit L2).

typedef __attribute__((ext_vector_type(4))) float f32x4;
typedef __attribute__((ext_vector_type(16))) float f32x16;
typedef __attribute__((ext_vector_type(8))) short s16x8;
typedef __attribute__((ext_vector_type(4))) unsigned int u32x4;

constexpr int D_ = 64;
constexpr int O_ = 256;
constexpr int M_ = 16 * 128 * 128;              // 262144
constexpr int ITERS = 2;
constexpr int PIX_PER_BLOCK = 4 * 32 * ITERS;   // 256
constexpr int NBLOCKS = M_ / PIX_PER_BLOCK;     // 1024

__device__ __forceinline__ unsigned short f2bf(float f) {
    // round-to-nearest-even fp32 -> bf16
    unsigned u = __builtin_bit_cast(unsigned, f);
    u += 0x7FFFu + ((u >> 16) & 1u);
    return (unsigned short)(u >> 16);
}

__global__ __launch_bounds__(256, 4) void dist_kernel(
    const float* __restrict__ x,
    const float* __restrict__ om,
    float* __restrict__ out)
{
    // [ (T*4+s)*64 + lane ]: 16B bf16 B-fragment of proto-tile T (32 protos),
    // k-step s. Lane (o=lane&31, h=lane>>5) holds omega[T*32+o][s*16+h*8 ..+8).
    __shared__ u32x4 lfrag[32 * 64];          // 32 KiB
    __shared__ __align__(16) float lp2[O_];   // 1 KiB

    const int tid  = threadIdx.x;
    const int wave = tid >> 6;
    const int lane = tid & 63;
    const int p    = lane & 31;   // A: pixel row ; B: proto col ; store col
    const int h    = lane >> 5;   // k-half

    // ---------- once per block: omega -> bf16 fragments + p2 ---------------
#pragma unroll
    for (int tt = 0; tt < 2; ++tt) {
        const int T = wave * 2 + tt;
        float p2p = 0.f;
#pragma unroll
        for (int s = 0; s < 4; ++s) {
            const float* src = om + (T * 32 + p) * D_ + s * 16 + h * 8;
            f32x4 v0 = *(const f32x4*)(src);
            f32x4 v1 = *(const f32x4*)(src + 4);
            s16x8 f;
#pragma unroll
            for (int j = 0; j < 4; ++j) {
                f[j]     = (short)f2bf(v0[j]); p2p += v0[j] * v0[j];
                f[4 + j] = (short)f2bf(v1[j]); p2p += v1[j] * v1[j];
            }
            lfrag[(T * 4 + s) * 64 + lane] = __builtin_bit_cast(u32x4, f);
        }
        p2p += __shfl_xor(p2p, 32);           // join the two k-halves
        if (lane < 32) lp2[T * 32 + p] = p2p;
    }
    __syncthreads();

    float p2r[8];
#pragma unroll
    for (int T = 0; T < 8; ++T) p2r[T] = lp2[T * 32 + p];  // 2-way bcast, free

    // ---------- steady state: 32 pixels per wave per iteration --------------
    const int pix0 = blockIdx.x * PIX_PER_BLOCK;

    for (int it = 0; it < ITERS; ++it) {
        const int rbase = pix0 + it * 128 + wave * 32;

        // A-frag: lane (p,h) holds x[rbase+p][s*16 + h*8 ..+8) for s=0..3
        const float* xs = x + (size_t)(rbase + p) * D_ + h * 8;
        s16x8 Af[4];
        float x2p = 0.f;
#pragma unroll
        for (int s = 0; s < 4; ++s) {
            f32x4 a0 = __builtin_nontemporal_load((const f32x4*)(xs + s * 16));
            f32x4 a1 = __builtin_nontemporal_load((const f32x4*)(xs + s * 16 + 4));
#pragma unroll
            for (int j = 0; j < 4; ++j) {
                Af[s][j]     = (short)f2bf(a0[j]); x2p += a0[j] * a0[j];
                Af[s][4 + j] = (short)f2bf(a1[j]); x2p += a1[j] * a1[j];
            }
        }
        x2p += __shfl_xor(x2p, 32);           // full ||x||^2 of pixel p

        // x2 for the 16 C-rows this lane will store: row = (reg&3)+8*(reg>>2)+4h
        float x2r[16];
#pragma unroll
        for (int reg = 0; reg < 16; ++reg)
            x2r[reg] = __shfl(x2p, (reg & 3) + 8 * (reg >> 2) + 4 * h);

        // base: row offset 4h baked in; col = p
        float* const obase = out + (size_t)(rbase + 4 * h) * O_ + p;

#pragma unroll
        for (int T = 0; T < 8; ++T) {
            f32x16 acc = {0.f, 0.f, 0.f, 0.f, 0.f, 0.f, 0.f, 0.f,
                          0.f, 0.f, 0.f, 0.f, 0.f, 0.f, 0.f, 0.f};
#pragma unroll
            for (int s = 0; s < 4; ++s) {
                s16x8 Bf = __builtin_bit_cast(s16x8, lfrag[(T * 4 + s) * 64 + lane]);
                acc = __builtin_amdgcn_mfma_f32_32x32x16_bf16(Af[s], Bf, acc, 0, 0, 0);
            }
            // epilogue + store: scalar dword, lanes 0..31 = protos T*32..+31
            // contiguous -> full 128B line requests; NONTEMPORAL (no-allocate)
#pragma unroll
            for (int reg = 0; reg < 16; ++reg) {
                const float val = (x2r[reg] + p2r[T]) - 2.f * acc[reg];
                __builtin_nontemporal_store(
                    val, &obase[((reg & 3) + 8 * (reg >> 2)) * O_ + T * 32]);
            }
        }
    }
}

extern "C" void kernel_launch(void* const* d_in, const int* in_sizes, int n_in,
                              void* d_out, int out_size, void* d_ws, size_t ws_size,
                              hipStream_t stream) {
    const float* x  = (const float*)d_in[0];   // [16,128,128,64] fp32
    const float* om = (const float*)d_in[1];   // [256,64] fp32
    float* out = (float*)d_out;                // [16,128,128,256,1] fp32

    dist_kernel<<<dim3(NBLOCKS), dim3(256), 0, stream>>>(x, om, out);
}

// Round 17
// 74.927 us; speedup vs baseline: 1.0544x; 1.0544x over previous
//
#include <hip/hip_runtime.h>

// dist[pix, o] = ||x[pix]||^2 + ||omega[o]||^2 - 2 * x.omega
// M = 262144 pixels, O = 256 protos, D = 64.
// Round-17: R13 base (32x32x16 MFMA, A=x / B=omega, nt loads, PLAIN stores,
// omega frags in LDS, 4 blocks/CU). Change: proto-tiles processed in PAIRS
// (T0,T1) with one shfl_xor(32) per store so each store instruction is a
// 64-lane contiguous dword run = one 256B request (R13: 32-lane = 128B).
// Coalescer rule learned R11/R13: request size = contiguous LANE RUN size.
// Mapping: C layout col=lane&31, row=(reg&3)+8*(reg>>2)+4*(lane>>5).
//  reg q: h=0 lanes hold row rb=(q&3)+8*(q>>2); h=1 lanes hold row rb+4.
//  store A (row rb):   lanes<32 own T0 value; lanes>=32 take shfl_xor(T1,32)
//                      (lane i gets lane i-32's T1 value: same col, row rb).
//  store B (row rb+4): lanes<32 take shfl_xor(T0,32); lanes>=32 own T1.
//  addr = out[(rbase+row)*O + T0*32 + lane] -> cols TP*64..+63 contiguous.
// Epilogue applied BEFORE the swap (values lane-complete), so the swap is a
// pure permutation of finished outputs.

typedef __attribute__((ext_vector_type(4))) float f32x4;
typedef __attribute__((ext_vector_type(16))) float f32x16;
typedef __attribute__((ext_vector_type(8))) short s16x8;
typedef __attribute__((ext_vector_type(4))) unsigned int u32x4;

constexpr int D_ = 64;
constexpr int O_ = 256;
constexpr int M_ = 16 * 128 * 128;              // 262144
constexpr int ITERS = 2;
constexpr int PIX_PER_BLOCK = 4 * 32 * ITERS;   // 256
constexpr int NBLOCKS = M_ / PIX_PER_BLOCK;     // 1024

__device__ __forceinline__ unsigned short f2bf(float f) {
    // round-to-nearest-even fp32 -> bf16
    unsigned u = __builtin_bit_cast(unsigned, f);
    u += 0x7FFFu + ((u >> 16) & 1u);
    return (unsigned short)(u >> 16);
}

__global__ __launch_bounds__(256, 4) void dist_kernel(
    const float* __restrict__ x,
    const float* __restrict__ om,
    float* __restrict__ out)
{
    // [ (T*4+s)*64 + lane ]: 16B bf16 B-fragment of proto-tile T (32 protos),
    // k-step s. Lane (o=lane&31, h=lane>>5) holds omega[T*32+o][s*16+h*8 ..+8).
    __shared__ u32x4 lfrag[32 * 64];          // 32 KiB
    __shared__ __align__(16) float lp2[O_];   // 1 KiB

    const int tid  = threadIdx.x;
    const int wave = tid >> 6;
    const int lane = tid & 63;
    const int p    = lane & 31;   // A: pixel row ; B: proto col ; store col
    const int h    = lane >> 5;   // k-half

    // ---------- once per block: omega -> bf16 fragments + p2 ---------------
#pragma unroll
    for (int tt = 0; tt < 2; ++tt) {
        const int T = wave * 2 + tt;
        float p2p = 0.f;
#pragma unroll
        for (int s = 0; s < 4; ++s) {
            const float* src = om + (T * 32 + p) * D_ + s * 16 + h * 8;
            f32x4 v0 = *(const f32x4*)(src);
            f32x4 v1 = *(const f32x4*)(src + 4);
            s16x8 f;
#pragma unroll
            for (int j = 0; j < 4; ++j) {
                f[j]     = (short)f2bf(v0[j]); p2p += v0[j] * v0[j];
                f[4 + j] = (short)f2bf(v1[j]); p2p += v1[j] * v1[j];
            }
            lfrag[(T * 4 + s) * 64 + lane] = __builtin_bit_cast(u32x4, f);
        }
        p2p += __shfl_xor(p2p, 32);           // join the two k-halves
        if (lane < 32) lp2[T * 32 + p] = p2p;
    }
    __syncthreads();

    float p2r[8];
#pragma unroll
    for (int T = 0; T < 8; ++T) p2r[T] = lp2[T * 32 + p];  // 2-way bcast, free

    // ---------- steady state: 32 pixels per wave per iteration --------------
    const int pix0 = blockIdx.x * PIX_PER_BLOCK;

    for (int it = 0; it < ITERS; ++it) {
        const int rbase = pix0 + it * 128 + wave * 32;

        // A-frag: lane (p,h) holds x[rbase+p][s*16 + h*8 ..+8) for s=0..3
        const float* xs = x + (size_t)(rbase + p) * D_ + h * 8;
        s16x8 Af[4];
        float x2p = 0.f;
#pragma unroll
        for (int s = 0; s < 4; ++s) {
            f32x4 a0 = __builtin_nontemporal_load((const f32x4*)(xs + s * 16));
            f32x4 a1 = __builtin_nontemporal_load((const f32x4*)(xs + s * 16 + 4));
#pragma unroll
            for (int j = 0; j < 4; ++j) {
                Af[s][j]     = (short)f2bf(a0[j]); x2p += a0[j] * a0[j];
                Af[s][4 + j] = (short)f2bf(a1[j]); x2p += a1[j] * a1[j];
            }
        }
        x2p += __shfl_xor(x2p, 32);           // full ||x||^2 of pixel p

        // x2 for this lane's 16 C-rows: row = (reg&3)+8*(reg>>2)+4h
        float x2r[16];
#pragma unroll
        for (int reg = 0; reg < 16; ++reg)
            x2r[reg] = __shfl(x2p, (reg & 3) + 8 * (reg >> 2) + 4 * h);

        // col base for the pair stores: T0*32 + lane (lane 0..63 contiguous)
        float* const obase = out + (size_t)rbase * O_ + lane;

#pragma unroll
        for (int TP = 0; TP < 4; ++TP) {
            const int T0 = 2 * TP, T1 = 2 * TP + 1;
            f32x16 acc0 = {0.f, 0.f, 0.f, 0.f, 0.f, 0.f, 0.f, 0.f,
                           0.f, 0.f, 0.f, 0.f, 0.f, 0.f, 0.f, 0.f};
            f32x16 acc1 = acc0;
#pragma unroll
            for (int s = 0; s < 4; ++s) {
                s16x8 Bf0 = __builtin_bit_cast(s16x8, lfrag[(T0 * 4 + s) * 64 + lane]);
                s16x8 Bf1 = __builtin_bit_cast(s16x8, lfrag[(T1 * 4 + s) * 64 + lane]);
                acc0 = __builtin_amdgcn_mfma_f32_32x32x16_bf16(Af[s], Bf0, acc0, 0, 0, 0);
                acc1 = __builtin_amdgcn_mfma_f32_32x32x16_bf16(Af[s], Bf1, acc1, 0, 0, 0);
            }
            float* const pb = obase + T0 * 32;
#pragma unroll
            for (int reg = 0; reg < 16; ++reg) {
                const int rb = (reg & 3) + 8 * (reg >> 2);   // row of h=0 lanes
                // epilogue first: lane-complete finished values
                const float e0 = (x2r[reg] + p2r[T0]) - 2.f * acc0[reg];
                const float e1 = (x2r[reg] + p2r[T1]) - 2.f * acc1[reg];
                // cross-half exchange (all lanes execute both shfls)
                const float r1 = __shfl_xor(e1, 32);
                const float r0 = __shfl_xor(e0, 32);
                const float sA = (lane < 32) ? e0 : r1;   // row rb,   64 cols
                const float sB = (lane < 32) ? r0 : e1;   // row rb+4, 64 cols
                pb[(size_t)rb * O_]       = sA;   // one 256B contiguous request
                pb[(size_t)(rb + 4) * O_] = sB;   // one 256B contiguous request
            }
        }
    }
}

extern "C" void kernel_launch(void* const* d_in, const int* in_sizes, int n_in,
                              void* d_out, int out_size, void* d_ws, size_t ws_size,
                              hipStream_t stream) {
    const float* x  = (const float*)d_in[0];   // [16,128,128,64] fp32
    const float* om = (const float*)d_in[1];   // [256,64] fp32
    float* out = (float*)d_out;                // [16,128,128,256,1] fp32

    dist_kernel<<<dim3(NBLOCKS), dim3(256), 0, stream>>>(x, om, out);
}

// Round 18
// 69.532 us; speedup vs baseline: 1.1362x; 1.0776x over previous
//
#include <hip/hip_runtime.h>

// dist[pix, o] = ||x[pix]||^2 + ||omega[o]||^2 - 2 * x.omega
// M = 262144 pixels, O = 256 protos, D = 64.
// Round-18: read-side restructure. R13's A-layout (row=lane&31) makes every
// x-load instr 64 isolated 16B requests (512 requests/wave-iter for 4x less
// data than the writes) -- the R11 pathology on the read path. Fix: block
// cooperatively stages 32 pixels (8KB) per iter into LDS with fully-coalesced
// 1KB-per-wave-instr loads (copy-kernel class), double-buffered; lanes then
// ds_read their A-fragments (padded stride 68 -> <=2-way bank alias = free).
// omega moves to per-wave REGISTERS (2 proto-tiles/wave, 32 VGPR) -- no
// omega LDS, no prologue barrier. Store path = exact R13 (scalar dword,
// 32-lane contiguous runs = full 128B line requests, plain). nt loads kept.

typedef __attribute__((ext_vector_type(4))) float f32x4;
typedef __attribute__((ext_vector_type(16))) float f32x16;
typedef __attribute__((ext_vector_type(8))) short s16x8;

constexpr int D_ = 64;
constexpr int O_ = 256;
constexpr int M_ = 16 * 128 * 128;                 // 262144
constexpr int ITERS = 8;
constexpr int PIX_PER_ITER = 32;
constexpr int PIX_PER_BLOCK = ITERS * PIX_PER_ITER; // 256
constexpr int NBLOCKS = M_ / PIX_PER_BLOCK;         // 1024
constexpr int LROW = 68;   // padded LDS row stride (floats): 64+4 kills bank alias

__device__ __forceinline__ unsigned short f2bf(float f) {
    // round-to-nearest-even fp32 -> bf16
    unsigned u = __builtin_bit_cast(unsigned, f);
    u += 0x7FFFu + ((u >> 16) & 1u);
    return (unsigned short)(u >> 16);
}

__global__ __launch_bounds__(256, 4) void dist_kernel(
    const float* __restrict__ x,
    const float* __restrict__ om,
    float* __restrict__ out)
{
    __shared__ float xstg[2][32 * LROW];   // 2 x 8704 B = 17408 B

    const int tid  = threadIdx.x;
    const int wave = tid >> 6;
    const int lane = tid & 63;
    const int p    = lane & 31;   // A: pixel row ; B: proto col ; store col
    const int h    = lane >> 5;   // k-half

    // ---------- omega -> per-wave register fragments (+ p2) -----------------
    // wave owns proto-tiles T = wave*2 + tt (64 protos). Identity k-map
    // k = s*16 + h*8 + j applied to BOTH A and B.
    s16x8 Bf[2][4];
    float p2r[2];
#pragma unroll
    for (int tt = 0; tt < 2; ++tt) {
        const int T = wave * 2 + tt;
        float p2p = 0.f;
#pragma unroll
        for (int s = 0; s < 4; ++s) {
            const float* src = om + (T * 32 + p) * D_ + s * 16 + h * 8;
            f32x4 v0 = *(const f32x4*)(src);
            f32x4 v1 = *(const f32x4*)(src + 4);
#pragma unroll
            for (int j = 0; j < 4; ++j) {
                Bf[tt][s][j]     = (short)f2bf(v0[j]); p2p += v0[j] * v0[j];
                Bf[tt][s][4 + j] = (short)f2bf(v1[j]); p2p += v1[j] * v1[j];
            }
        }
        p2p += __shfl_xor(p2p, 32);   // join k-halves: full ||omega[T*32+p]||^2
        p2r[tt] = p2p;
    }

    // ---------- staging helpers --------------------------------------------
    const size_t gbase = (size_t)blockIdx.x * PIX_PER_BLOCK * D_;
    const int sr = tid >> 4;              // staging row 0..15
    const int sc = (tid & 15) * 4;        // staging col (floats)

    // prologue: stage iter 0 (coalesced: each wave = 1KB contiguous runs)
    {
        const float* src = x + gbase + tid * 4;
        f32x4 v0 = __builtin_nontemporal_load((const f32x4*)(src));
        f32x4 v1 = __builtin_nontemporal_load((const f32x4*)(src + 1024));
        *(f32x4*)&xstg[0][sr * LROW + sc] = v0;
        *(f32x4*)&xstg[0][(16 + sr) * LROW + sc] = v1;
    }
    __syncthreads();

    for (int it = 0; it < ITERS; ++it) {
        const int cur = it & 1, nxt = cur ^ 1;
        const int rbase = blockIdx.x * PIX_PER_BLOCK + it * PIX_PER_ITER;

        // ---- issue next tile's global loads early (hide under compute) ----
        f32x4 nv0, nv1;
        const bool pf = (it + 1 < ITERS);
        if (pf) {
            const float* src = x + gbase + (size_t)(it + 1) * (PIX_PER_ITER * D_) + tid * 4;
            nv0 = __builtin_nontemporal_load((const f32x4*)(src));
            nv1 = __builtin_nontemporal_load((const f32x4*)(src + 1024));
        }

        // ---- A-frags from LDS + exact ||x||^2 ----
        const float* row = &xstg[cur][p * LROW + h * 8];
        s16x8 Af[4];
        float x2p = 0.f;
#pragma unroll
        for (int s = 0; s < 4; ++s) {
            f32x4 a0 = *(const f32x4*)(row + s * 16);
            f32x4 a1 = *(const f32x4*)(row + s * 16 + 4);
#pragma unroll
            for (int j = 0; j < 4; ++j) {
                Af[s][j]     = (short)f2bf(a0[j]); x2p += a0[j] * a0[j];
                Af[s][4 + j] = (short)f2bf(a1[j]); x2p += a1[j] * a1[j];
            }
        }
        x2p += __shfl_xor(x2p, 32);

        // x2 for this lane's 16 C-rows: row = (reg&3)+8*(reg>>2)+4h
        float x2r[16];
#pragma unroll
        for (int reg = 0; reg < 16; ++reg)
            x2r[reg] = __shfl(x2p, (reg & 3) + 8 * (reg >> 2) + 4 * h);

        // ---- compute + store the wave's 2 proto-tiles (R13 store geometry)
#pragma unroll
        for (int tt = 0; tt < 2; ++tt) {
            const int T = wave * 2 + tt;
            f32x16 acc = {0.f, 0.f, 0.f, 0.f, 0.f, 0.f, 0.f, 0.f,
                          0.f, 0.f, 0.f, 0.f, 0.f, 0.f, 0.f, 0.f};
#pragma unroll
            for (int s = 0; s < 4; ++s)
                acc = __builtin_amdgcn_mfma_f32_32x32x16_bf16(Af[s], Bf[tt][s], acc, 0, 0, 0);

            float* const obase = out + (size_t)(rbase + 4 * h) * O_ + T * 32 + p;
#pragma unroll
            for (int reg = 0; reg < 16; ++reg) {
                const float val = (x2r[reg] + p2r[tt]) - 2.f * acc[reg];
                obase[((reg & 3) + 8 * (reg >> 2)) * O_] = val;
            }
        }

        // ---- commit staged tile, flip ----
        if (pf) {
            *(f32x4*)&xstg[nxt][sr * LROW + sc] = nv0;
            *(f32x4*)&xstg[nxt][(16 + sr) * LROW + sc] = nv1;
        }
        __syncthreads();
    }
}

extern "C" void kernel_launch(void* const* d_in, const int* in_sizes, int n_in,
                              void* d_out, int out_size, void* d_ws, size_t ws_size,
                              hipStream_t stream) {
    const float* x  = (const float*)d_in[0];   // [16,128,128,64] fp32
    const float* om = (const float*)d_in[1];   // [256,64] fp32
    float* out = (float*)d_out;                // [16,128,128,256,1] fp32

    dist_kernel<<<dim3(NBLOCKS), dim3(256), 0, stream>>>(x, om, out);
}

// Round 19
// 67.596 us; speedup vs baseline: 1.1688x; 1.0286x over previous
//
#include <hip/hip_runtime.h>

// dist[pix, o] = ||x[pix]||^2 + ||omega[o]||^2 - 2 * x.omega
// M = 262144 pixels, O = 256 protos, D = 64.
// Round-19: R18 base (coalesced LDS-staged x, omega in per-wave regs, 32x32
// MFMA, R13 store geometry, nt loads, plain stores). Single mechanism change:
// DECOUPLE STORE DRAIN FROM THE BARRIER. __syncthreads = s_waitcnt vmcnt(0)
// + s_barrier -> every iter stalled on its own 64 stores retiring. Now:
// triple-buffered LDS, prefetch 2 tiles ahead (two named reg sets), commit
// tile i+1 then RAW s_barrier with only lgkmcnt(0) (inline asm), stores AFTER
// the barrier. In-order vmcnt: ds_write waits only on 2-iter-old loads
// (counted wait, no store drain); stores retire a full compute phase later.

typedef __attribute__((ext_vector_type(4))) float f32x4;
typedef __attribute__((ext_vector_type(16))) float f32x16;
typedef __attribute__((ext_vector_type(8))) short s16x8;

constexpr int D_ = 64;
constexpr int O_ = 256;
constexpr int M_ = 16 * 128 * 128;                  // 262144
constexpr int ITERS = 8;
constexpr int PIX_PER_ITER = 32;
constexpr int PIX_PER_BLOCK = ITERS * PIX_PER_ITER; // 256
constexpr int NBLOCKS = M_ / PIX_PER_BLOCK;         // 1024
constexpr int LROW = 68;   // padded LDS row stride (floats)

__device__ __forceinline__ unsigned short f2bf(float f) {
    // round-to-nearest-even fp32 -> bf16
    unsigned u = __builtin_bit_cast(unsigned, f);
    u += 0x7FFFu + ((u >> 16) & 1u);
    return (unsigned short)(u >> 16);
}

// raw barrier: LDS visibility only (lgkmcnt), NO vmcnt drain
#define LDS_BARRIER() do {                                        \
    asm volatile("s_waitcnt lgkmcnt(0)" ::: "memory");            \
    __builtin_amdgcn_sched_barrier(0);                            \
    __builtin_amdgcn_s_barrier();                                 \
    __builtin_amdgcn_sched_barrier(0);                            \
} while (0)

__global__ __launch_bounds__(256, 4) void dist_kernel(
    const float* __restrict__ x,
    const float* __restrict__ om,
    float* __restrict__ out)
{
    __shared__ float xstg[3][32 * LROW];   // 3 x 8704 B = 26112 B

    const int tid  = threadIdx.x;
    const int wave = tid >> 6;
    const int lane = tid & 63;
    const int p    = lane & 31;   // A: pixel row ; B: proto col ; store col
    const int h    = lane >> 5;   // k-half

    // ---------- omega -> per-wave register fragments (+ p2) -----------------
    s16x8 Bf0[4], Bf1[4];
    float p2r0 = 0.f, p2r1 = 0.f;
#pragma unroll
    for (int tt = 0; tt < 2; ++tt) {
        const int T = wave * 2 + tt;
        float p2p = 0.f;
#pragma unroll
        for (int s = 0; s < 4; ++s) {
            const float* src = om + (T * 32 + p) * D_ + s * 16 + h * 8;
            f32x4 v0 = *(const f32x4*)(src);
            f32x4 v1 = *(const f32x4*)(src + 4);
            s16x8 f;
#pragma unroll
            for (int j = 0; j < 4; ++j) {
                f[j]     = (short)f2bf(v0[j]); p2p += v0[j] * v0[j];
                f[4 + j] = (short)f2bf(v1[j]); p2p += v1[j] * v1[j];
            }
            if (tt == 0) Bf0[s] = f; else Bf1[s] = f;
        }
        p2p += __shfl_xor(p2p, 32);
        if (tt == 0) p2r0 = p2p; else p2r1 = p2p;
    }

    // ---------- staging geometry -------------------------------------------
    const size_t gbase = (size_t)blockIdx.x * PIX_PER_BLOCK * D_;
    const int sr = tid >> 4;              // staging row 0..15
    const int sc = (tid & 15) * 4;        // staging col (floats)

    // prologue: commit tile0, preload tile1 into set B
    f32x4 nva0, nva1, nvb0, nvb1;
    {
        const float* s0 = x + gbase + tid * 4;
        f32x4 t0 = __builtin_nontemporal_load((const f32x4*)(s0));
        f32x4 t1 = __builtin_nontemporal_load((const f32x4*)(s0 + 1024));
        const float* s1 = x + gbase + 2048 + tid * 4;
        nvb0 = __builtin_nontemporal_load((const f32x4*)(s1));
        nvb1 = __builtin_nontemporal_load((const f32x4*)(s1 + 1024));
        *(f32x4*)&xstg[0][sr * LROW + sc] = t0;
        *(f32x4*)&xstg[0][(16 + sr) * LROW + sc] = t1;
    }
    __syncthreads();   // prologue only

#pragma unroll
    for (int it = 0; it < ITERS; ++it) {
        const int rbase = blockIdx.x * PIX_PER_BLOCK + it * PIX_PER_ITER;

        // ---- issue loads for tile it+2 into set (it&1): A=even, B=odd ----
        if (it + 2 < ITERS) {
            const float* s = x + gbase + (size_t)(it + 2) * (PIX_PER_ITER * D_) + tid * 4;
            if ((it & 1) == 0) {
                nva0 = __builtin_nontemporal_load((const f32x4*)(s));
                nva1 = __builtin_nontemporal_load((const f32x4*)(s + 1024));
            } else {
                nvb0 = __builtin_nontemporal_load((const f32x4*)(s));
                nvb1 = __builtin_nontemporal_load((const f32x4*)(s + 1024));
            }
        }

        // ---- A-frags from LDS + exact ||x||^2 ----
        const float* row = &xstg[it % 3][p * LROW + h * 8];
        s16x8 Af[4];
        float x2p = 0.f;
#pragma unroll
        for (int s = 0; s < 4; ++s) {
            f32x4 a0 = *(const f32x4*)(row + s * 16);
            f32x4 a1 = *(const f32x4*)(row + s * 16 + 4);
#pragma unroll
            for (int j = 0; j < 4; ++j) {
                Af[s][j]     = (short)f2bf(a0[j]); x2p += a0[j] * a0[j];
                Af[s][4 + j] = (short)f2bf(a1[j]); x2p += a1[j] * a1[j];
            }
        }
        x2p += __shfl_xor(x2p, 32);

        // ---- MFMA: the wave's 2 proto-tiles ----
        f32x16 acc0 = {0.f, 0.f, 0.f, 0.f, 0.f, 0.f, 0.f, 0.f,
                       0.f, 0.f, 0.f, 0.f, 0.f, 0.f, 0.f, 0.f};
        f32x16 acc1 = acc0;
#pragma unroll
        for (int s = 0; s < 4; ++s) {
            acc0 = __builtin_amdgcn_mfma_f32_32x32x16_bf16(Af[s], Bf0[s], acc0, 0, 0, 0);
            acc1 = __builtin_amdgcn_mfma_f32_32x32x16_bf16(Af[s], Bf1[s], acc1, 0, 0, 0);
        }

        // ---- commit tile it+1 (loaded 1 iter ago, set (it+1)&1) ----
        if (it + 1 < ITERS) {
            float* dst = &xstg[(it + 1) % 3][0];
            if (((it + 1) & 1) == 0) {
                *(f32x4*)&dst[sr * LROW + sc] = nva0;
                *(f32x4*)&dst[(16 + sr) * LROW + sc] = nva1;
            } else {
                *(f32x4*)&dst[sr * LROW + sc] = nvb0;
                *(f32x4*)&dst[(16 + sr) * LROW + sc] = nvb1;
            }
            LDS_BARRIER();   // lgkmcnt only — stores stay in flight
        }

        // ---- stores AFTER the barrier (R13 geometry, plain dword) ----
        const int T0 = wave * 2;
        float* const ob0 = out + (size_t)(rbase + 4 * h) * O_ + T0 * 32 + p;
#pragma unroll
        for (int reg = 0; reg < 16; ++reg) {
            const int r = (reg & 3) + 8 * (reg >> 2);
            const float x2v = __shfl(x2p, r + 4 * h);
            ob0[(size_t)r * O_]      = (x2v + p2r0) - 2.f * acc0[reg];
            ob0[(size_t)r * O_ + 32] = (x2v + p2r1) - 2.f * acc1[reg];
        }
    }
}

extern "C" void kernel_launch(void* const* d_in, const int* in_sizes, int n_in,
                              void* d_out, int out_size, void* d_ws, size_t ws_size,
                              hipStream_t stream) {
    const float* x  = (const float*)d_in[0];   // [16,128,128,64] fp32
    const float* om = (const float*)d_in[1];   // [256,64] fp32
    float* out = (float*)d_out;                // [16,128,128,256,1] fp32

    dist_kernel<<<dim3(NBLOCKS), dim3(256), 0, stream>>>(x, om, out);
}